// Round 12
// baseline (276.877 us; speedup 1.0000x reference)
//
#include <hip/hip_runtime.h>
#include <hip/hip_bf16.h>
#include <math.h>

// Problem constants (fixed by reference setup_inputs)
#define BB 16
#define NN 64
#define ATTR 4
#define STATE 16
#define RELD 9
#define GG 32
#define NF 256
#define NROWS_OBJ (BB*NN)        // 1024
#define NROWS_REL (BB*NN*NN)     // 65536

typedef _Float16 half8 __attribute__((ext_vector_type(8)));
typedef float  floatx4 __attribute__((ext_vector_type(4)));
typedef unsigned short ushort_t;

// fp16 split: x ~= h + l, |x-(h+l)| ~ 2^-22 |x| (A-operand use only)
__device__ __forceinline__ void split2h(float x, _Float16& h, _Float16& l) {
  h = (_Float16)x;
  l = (_Float16)(x - (float)h);
}

#define F0_ELEMS (2 * 16 * 64 * 8)   // 16384
#define F1_ELEMS (8 * 16 * 64 * 8)   // 65536
#define F_TOTAL  (F0_ELEMS + 2 * F1_ELEMS)

// Staged GEMM accumulate: weights pulled global->LDS once per block per chunk
// (float4, each 64B line fetched exactly once), FMAs read from LDS.
// Requires: __shared__ float Ws[32*NF]; tid in [0,1024); r,c as row/col.
#define STAGED_ACC(acc_, SRC, W) do { \
  for (int k0 = 0; k0 < NF; k0 += 32) { \
    __syncthreads(); \
    const float4* _s = (const float4*)((W) + (size_t)k0 * NF); \
    float4* _d = (float4*)Ws; \
    _d[tid] = _s[tid]; \
    _d[tid + 1024] = _s[tid + 1024]; \
    __syncthreads(); \
    _Pragma("unroll") \
    for (int k = 0; k < 32; ++k) \
      acc_ += (SRC)[r * NF + k0 + k] * Ws[k * NF + c]; \
  } } while (0)

// ---------------------------------------------------------------------------
// Fused encoder + Q/R + weight-fragment prep. Weights single fp16 for the
// MFMA rel chain (proven R10). GEMM loops now LDS-staged (STAGED_ACC).
// ---------------------------------------------------------------------------
__global__ __launch_bounds__(1024) void enc_qr_prep_kernel(
    const float* __restrict__ attrs, const float* __restrict__ states,
    const float* __restrict__ w0, const float* __restrict__ b0,
    const float* __restrict__ w1, const float* __restrict__ b1,
    const float* __restrict__ rpw, const float* __restrict__ rpb,
    const float* __restrict__ rel_w0, const float* __restrict__ rel_w1,
    _Float16* __restrict__ F0, _Float16* __restrict__ F1,
    _Float16* __restrict__ F2,
    float* __restrict__ obj, float* __restrict__ Q, float* __restrict__ R)
{
  int tid = threadIdx.x;
  for (int idx = blockIdx.x * 1024 + tid; idx < F_TOTAL; idx += 256 * 1024) {
    if (idx < F0_ELEMS) {
      int j = idx & 7, lane = (idx >> 3) & 63, g = (idx >> 9) & 15, s = idx >> 13;
      int k = s * 32 + (lane >> 4) * 8 + j, n = g * 16 + (lane & 15);
      float v = (k < 33) ? rel_w0[k * NF + n] : 0.f;
      F0[idx] = (_Float16)v;
    } else if (idx < F0_ELEMS + F1_ELEMS) {
      int t = idx - F0_ELEMS;
      int j = t & 7, lane = (t >> 3) & 63, g = (t >> 9) & 15, s = t >> 13;
      int k = s * 32 + (lane >> 4) * 8 + j, n = g * 16 + (lane & 15);
      F1[t] = (_Float16)rel_w1[k * NF + n];
    } else {
      int t = idx - (F0_ELEMS + F1_ELEMS);
      int j = t & 7, lane = (t >> 3) & 63, g = (t >> 9) & 15, s = t >> 13;
      int k = s * 32 + (lane >> 4) * 8 + j, n = g * 16 + (lane & 15);
      F2[t] = (_Float16)rpw[k * NF + n];
    }
  }
  __shared__ float X[4 * 20];
  __shared__ float H[4 * NF];
  __shared__ float O[4 * NF];
  __shared__ __align__(16) float Ws[32 * NF];
  int row0 = blockIdx.x * 4;
  if (tid < 80) {
    int r = tid / 20, k = tid % 20;
    int m = row0 + r;
    X[tid] = (k < ATTR) ? attrs[m * ATTR + k] : states[m * STATE + (k - ATTR)];
  }
  __syncthreads();
  int r = tid >> 8, c = tid & 255;
  float a = b0[c];
#pragma unroll
  for (int k = 0; k < 20; ++k) a += X[r * 20 + k] * w0[k * NF + c];
  H[r * NF + c] = fmaxf(a, 0.f);
  a = b1[c];
  STAGED_ACC(a, H, w1);
  a = fmaxf(a, 0.f);
  O[r * NF + c] = a;
  obj[(row0 + r) * NF + c] = a;
  a = rpb[c];
  STAGED_ACC(a, O, rpw + 256 * NF);
  Q[(row0 + r) * NF + c] = a;
  a = 0.f;
  STAGED_ACC(a, O, rpw + 512 * NF);
  R[(row0 + r) * NF + c] = a;
}

// ---------------------------------------------------------------------------
// Relation chain, fp16 A-split x B-single MFMA (FROZEN from R10: 59us,
// absmax 0.0156): run ONCE, stage-3 P-tile in regs -> fp32 P store + fused
// pstep-1 aggregation epilogue.
// ---------------------------------------------------------------------------
#define ROWS 32
#define NRT 2
#define HSTR 264
#define XSTR 72

__global__ __launch_bounds__(256, 4) void rel_agg_store_mfma(
    const float* __restrict__ attrs, const float* __restrict__ states,
    const float* __restrict__ rel_attrs,
    const _Float16* __restrict__ F0, const float* __restrict__ b0,
    const _Float16* __restrict__ F1, const float* __restrict__ b1,
    const _Float16* __restrict__ F2,
    const float* __restrict__ Q, const float* __restrict__ R,
    float* __restrict__ P, float* __restrict__ part)
{
  __shared__ __align__(16) _Float16 S[2 * ROWS * HSTR];   // 33792 B
  _Float16* Hh = S;
  _Float16* Hl = S + ROWS * HSTR;
  _Float16* Xh = Hh;   // X aliased onto H (dead after stage 1)
  _Float16* Xl = Hl;

  int tid  = threadIdx.x;
  int wave = tid >> 6;
  int lane = tid & 63;
  int quad = lane >> 4;
  int l16  = lane & 15;
  int row0 = blockIdx.x * ROWS;

  for (int idx = tid; idx < ROWS * 64; idx += 256) {
    int r = idx >> 6, k = idx & 63;
    int grow = row0 + r;
    int j = grow & 63, i = (grow >> 6) & 63, b = grow >> 12;
    float v = 0.f;
    if (k < RELD)                     v = rel_attrs[(size_t)grow * RELD + k];
    else if (k < RELD + STATE)        v = states[(b * NN + i) * STATE + (k - RELD)]
                                        - states[(b * NN + j) * STATE + (k - RELD)];
    else if (k < RELD + STATE + ATTR) v = attrs[(b * NN + i) * ATTR + (k - RELD - STATE)];
    else if (k < 33)                  v = attrs[(b * NN + j) * ATTR + (k - RELD - STATE - ATTR)];
    _Float16 h, l; split2h(v, h, l);
    Xh[r * XSTR + k] = h;
    Xl[r * XSTR + k] = l;
  }
  __syncthreads();

  floatx4 acc[NRT][4];

#define ZERO_ACC() do { \
  _Pragma("unroll") for (int rt = 0; rt < NRT; ++rt) \
  _Pragma("unroll") for (int ct = 0; ct < 4; ++ct) acc[rt][ct] = (floatx4)(0.f); } while (0)

#define STAGE(Sn, AH, AL, ASTR, BF) do { \
  half8 ah[2][NRT], al[2][NRT], bf[2][4]; \
  _Pragma("unroll") for (int ct = 0; ct < 4; ++ct) \
    bf[0][ct] = *(const half8*)((BF) + (size_t)((wave * 4 + ct) * 64 + lane) * 8); \
  _Pragma("unroll") for (int rt = 0; rt < NRT; ++rt) { \
    ah[0][rt] = *(const half8*)(&(AH)[(rt * 16 + l16) * (ASTR) + quad * 8]); \
    al[0][rt] = *(const half8*)(&(AL)[(rt * 16 + l16) * (ASTR) + quad * 8]); } \
  _Pragma("unroll") \
  for (int s = 0; s < (Sn); ++s) { \
    int cur = s & 1, nxt = cur ^ 1; \
    if (s + 1 < (Sn)) { \
      _Pragma("unroll") for (int ct = 0; ct < 4; ++ct) \
        bf[nxt][ct] = *(const half8*)((BF) + (size_t)(((s + 1) * 16 + wave * 4 + ct) * 64 + lane) * 8); \
      _Pragma("unroll") for (int rt = 0; rt < NRT; ++rt) { \
        ah[nxt][rt] = *(const half8*)(&(AH)[(rt * 16 + l16) * (ASTR) + (s + 1) * 32 + quad * 8]); \
        al[nxt][rt] = *(const half8*)(&(AL)[(rt * 16 + l16) * (ASTR) + (s + 1) * 32 + quad * 8]); } } \
    _Pragma("unroll") for (int rt = 0; rt < NRT; ++rt) \
    _Pragma("unroll") for (int ct = 0; ct < 4; ++ct) { \
      acc[rt][ct] = __builtin_amdgcn_mfma_f32_16x16x32_f16(ah[cur][rt], bf[cur][ct], acc[rt][ct], 0, 0, 0); \
      acc[rt][ct] = __builtin_amdgcn_mfma_f32_16x16x32_f16(al[cur][rt], bf[cur][ct], acc[rt][ct], 0, 0, 0); } \
  } } while (0)

  // ---- stage 1: H = ReLU(X @ W0 + b0), K=64 (padded)
  ZERO_ACC();
  STAGE(2, Xh, Xl, XSTR, F0);
  __syncthreads();  // X reads done before H overwrites the aliased region
#pragma unroll
  for (int ct = 0; ct < 4; ++ct) {
    int col = wave * 64 + ct * 16 + l16;
    float bias = b0[col];
#pragma unroll
    for (int rt = 0; rt < NRT; ++rt)
#pragma unroll
      for (int r = 0; r < 4; ++r) {
        int row = rt * 16 + quad * 4 + r;
        float h = fmaxf(acc[rt][ct][r] + bias, 0.f);
        split2h(h, Hh[row * HSTR + col], Hl[row * HSTR + col]);
      }
  }
  __syncthreads();

  // ---- stage 2: E = ReLU(H @ W1 + b1), K=256
  ZERO_ACC();
  STAGE(8, Hh, Hl, HSTR, F1);
  __syncthreads();
#pragma unroll
  for (int ct = 0; ct < 4; ++ct) {
    int col = wave * 64 + ct * 16 + l16;
    float bias = b1[col];
#pragma unroll
    for (int rt = 0; rt < NRT; ++rt)
#pragma unroll
      for (int r = 0; r < 4; ++r) {
        int row = rt * 16 + quad * 4 + r;
        float e = fmaxf(acc[rt][ct][r] + bias, 0.f);
        split2h(e, Hh[row * HSTR + col], Hl[row * HSTR + col]);
      }
  }
  __syncthreads();

  // ---- stage 3: P-tile in registers (K=256)
  ZERO_ACC();
  STAGE(8, Hh, Hl, HSTR, F2);

  // ---- store P fp32 (pstep 2 reads it via agg_part)
#pragma unroll
  for (int ct = 0; ct < 4; ++ct) {
    int col = wave * 64 + ct * 16 + l16;
#pragma unroll
    for (int rt = 0; rt < NRT; ++rt)
#pragma unroll
      for (int r = 0; r < 4; ++r) {
        int row = rt * 16 + quad * 4 + r;
        P[(size_t)(row0 + row) * NF + col] = acc[rt][ct][r];
      }
  }
  __syncthreads();                       // all E reads done — LDS reusable

  // ---- fused pstep-1 aggregation epilogue
  {
    float* Rs = (float*)S;               // 32 x 256 fp32 R-tile (32KB)
    int bi    = row0 >> 6;
    int jbase = row0 & 63;               // 0 or 32
    int b     = row0 >> 12;
    for (int idx = tid; idx < ROWS * NF; idx += 256) {
      int rr = idx >> 8, cc = idx & 255;
      Rs[idx] = R[(size_t)(b * NN + jbase + rr) * NF + cc];
    }
    __syncthreads();
#pragma unroll
    for (int ct = 0; ct < 4; ++ct) {
      int col = wave * 64 + ct * 16 + l16;
      float q = Q[bi * NF + col];
      float s = 0.f;
#pragma unroll
      for (int rt = 0; rt < NRT; ++rt)
#pragma unroll
        for (int r = 0; r < 4; ++r) {
          int row = rt * 16 + quad * 4 + r;
          s += fmaxf(acc[rt][ct][r] + q + Rs[row * NF + col], 0.f);
        }
      s += __shfl_xor(s, 16, 64);        // quad butterfly: rows 0..31 summed
      s += __shfl_xor(s, 32, 64);
      if (quad == 0)
        part[((size_t)bi * 2 + (jbase >> 5)) * NF + col] = s;
    }
  }
#undef ZERO_ACC
#undef STAGE
}

// ---------------------------------------------------------------------------
// upd_qr: G = part1 halves summed; obj' = ReLU([obj,G]@pp_w+pp_b); Q',R'.
// GEMM loops LDS-staged (weight lines fetched once per block).
// ---------------------------------------------------------------------------
__global__ __launch_bounds__(1024) void upd_qr_kernel(
    const float* __restrict__ part, const float* __restrict__ obj,
    const float* __restrict__ ppw, const float* __restrict__ ppb,
    const float* __restrict__ rpw, const float* __restrict__ rpb,
    float* __restrict__ obj_out, float* __restrict__ Qo, float* __restrict__ Ro)
{
  __shared__ float A[4 * NF];
  __shared__ float G[4 * NF];
  __shared__ __align__(16) float Ws[32 * NF];
  int tid = threadIdx.x;
  int row0 = blockIdx.x * 4;
  int r = tid >> 8, c = tid & 255;
  A[r * NF + c] = obj[(row0 + r) * NF + c];
  G[r * NF + c] = part[((size_t)(row0 + r) * 2 + 0) * NF + c]
                + part[((size_t)(row0 + r) * 2 + 1) * NF + c];
  float a = ppb[c];
  STAGED_ACC(a, A, ppw);
  STAGED_ACC(a, G, ppw + NF * NF);
  float o = fmaxf(a, 0.f);
  __syncthreads();                 // all reads of old A done
  A[r * NF + c] = o;
  obj_out[(row0 + r) * NF + c] = o;
  a = rpb[c];
  STAGED_ACC(a, A, rpw + 256 * NF);
  Qo[(row0 + r) * NF + c] = a;
  a = 0.f;
  STAGED_ACC(a, A, rpw + 512 * NF);
  Ro[(row0 + r) * NF + c] = a;
}

// ---------------------------------------------------------------------------
// pstep-2 agg partials: part2[jg][bi][c] = sum_{j in jg*8..+8} ReLU(P+Q+R)
// grid (1024,8) = 32 waves/CU. (frozen)
// ---------------------------------------------------------------------------
__global__ __launch_bounds__(256) void agg_part_kernel(
    const float* __restrict__ P, const float* __restrict__ Q,
    const float* __restrict__ R, float* __restrict__ part)
{
  int bi = blockIdx.x;
  int jg = blockIdx.y;
  int c = threadIdx.x;
  int b = bi >> 6;
  float q = Q[bi * NF + c];
  const float* Pr = P + ((size_t)bi * NN + jg * 8) * NF + c;
  const float* Rr = R + (b * NN + jg * 8) * NF + c;
  float s = 0.f;
#pragma unroll
  for (int j = 0; j < 8; ++j)
    s += fmaxf(Pr[j * NF] + q + Rr[j * NF], 0.f);
  part[((size_t)jg * NROWS_OBJ + bi) * NF + c] = s;
}

// ---------------------------------------------------------------------------
// Final update + predictor; GEMM loops LDS-staged.
// ---------------------------------------------------------------------------
__global__ __launch_bounds__(1024) void upd_pred_kernel(
    const float* __restrict__ part, const float* __restrict__ obj,
    const float* __restrict__ ppw, const float* __restrict__ ppb,
    const float* __restrict__ w0, const float* __restrict__ b0,
    const float* __restrict__ w1, const float* __restrict__ b1,
    float* __restrict__ out)
{
  __shared__ float A[4 * NF];
  __shared__ float G[4 * NF];
  __shared__ __align__(16) float Ws[32 * NF];
  int tid = threadIdx.x;
  int row0 = blockIdx.x * 4;
  int r = tid >> 8, c = tid & 255;
  A[r * NF + c] = obj[(row0 + r) * NF + c];
  {
    float s = 0.f;
#pragma unroll
    for (int jg = 0; jg < 8; ++jg)
      s += part[((size_t)jg * NROWS_OBJ + row0 + r) * NF + c];
    G[r * NF + c] = s;
  }
  float a = ppb[c];
  STAGED_ACC(a, A, ppw);
  STAGED_ACC(a, G, ppw + NF * NF);
  float o = fmaxf(a, 0.f);
  __syncthreads();                 // old A reads done
  A[r * NF + c] = o;
  a = b0[c];
  STAGED_ACC(a, A, w0);
  __syncthreads();                 // G reads (2nd loop) long done; reuse G for T
  G[r * NF + c] = fmaxf(a, 0.f);
  __syncthreads();
  if (tid < 4 * GG) {
    int rr = tid >> 5, g = tid & 31;
    a = b1[g];
    const float* Tr = G + rr * NF;
#pragma unroll 8
    for (int k = 0; k < NF; ++k) a += Tr[k] * w1[k * GG + g];
    out[(row0 + rr) * GG + g] = tanhf(a);
  }
}

extern "C" void kernel_launch(void* const* d_in, const int* in_sizes, int n_in,
                              void* d_out, int out_size, void* d_ws, size_t ws_size,
                              hipStream_t stream)
{
  const float* attrs     = (const float*)d_in[0];
  const float* states    = (const float*)d_in[1];
  const float* rel_attrs = (const float*)d_in[2];
  // d_in[3] = pstep (==2, structural)
  const float* enc_w0  = (const float*)d_in[4];
  const float* enc_b0  = (const float*)d_in[5];
  const float* enc_w1  = (const float*)d_in[6];
  const float* enc_b1  = (const float*)d_in[7];
  const float* rel_w0  = (const float*)d_in[8];
  const float* rel_b0  = (const float*)d_in[9];
  const float* rel_w1  = (const float*)d_in[10];
  const float* rel_b1  = (const float*)d_in[11];
  const float* rp_w    = (const float*)d_in[12];
  const float* rp_b    = (const float*)d_in[13];
  const float* pp_w    = (const float*)d_in[14];
  const float* pp_b    = (const float*)d_in[15];
  const float* pred_w0 = (const float*)d_in[16];
  const float* pred_b0 = (const float*)d_in[17];
  const float* pred_w1 = (const float*)d_in[18];
  const float* pred_b1 = (const float*)d_in[19];
  float* out = (float*)d_out;

  char* ws = (char*)d_ws;
  float* P     = (float*)ws;                                // 64 MB
  float* obj0  = P + (size_t)NROWS_REL * NF;
  float* obj1  = obj0 + NROWS_OBJ * NF;
  float* Q0    = obj1 + NROWS_OBJ * NF;
  float* R0    = Q0 + NROWS_OBJ * NF;
  float* Q1    = R0 + NROWS_OBJ * NF;
  float* R1    = Q1 + NROWS_OBJ * NF;
  float* part1 = R1 + NROWS_OBJ * NF;                       // 2 MB
  float* part2 = part1 + 2 * (size_t)NROWS_OBJ * NF;        // 8 MB
  _Float16* F0 = (_Float16*)(part2 + 8 * (size_t)NROWS_OBJ * NF);
  _Float16* F1 = F0 + F0_ELEMS;
  _Float16* F2 = F1 + F1_ELEMS;

  enc_qr_prep_kernel<<<NROWS_OBJ / 4, 1024, 0, stream>>>(
      attrs, states, enc_w0, enc_b0, enc_w1, enc_b1, rp_w, rp_b,
      rel_w0, rel_w1, F0, F1, F2, obj0, Q0, R0);
  // rel chain ONCE: fused pstep-1 agg + fp32 P store for pstep 2
  rel_agg_store_mfma<<<NROWS_REL / ROWS, 256, 0, stream>>>(
      attrs, states, rel_attrs,
      F0, rel_b0, F1, rel_b1, F2,
      Q0, R0, P, part1);
  upd_qr_kernel<<<NROWS_OBJ / 4, 1024, 0, stream>>>(part1, obj0, pp_w, pp_b,
                                                    rp_w, rp_b, obj1, Q1, R1);
  // pstep 2: high-parallelism P sweep + final update/predictor
  agg_part_kernel<<<dim3(NROWS_OBJ, 8), 256, 0, stream>>>(P, Q1, R1, part2);
  upd_pred_kernel<<<NROWS_OBJ / 4, 1024, 0, stream>>>(part2, obj1, pp_w, pp_b,
                                                      pred_w0, pred_b0,
                                                      pred_w1, pred_b1, out);
}